// Round 8
// baseline (421.339 us; speedup 1.0000x reference)
//
#include <hip/hip_runtime.h>
#include <hip/hip_fp16.h>

#define BB 8
#define NN 1024
#define FF 128
#define HH 8

typedef _Float16 f16;
typedef f16  f16x8 __attribute__((ext_vector_type(8)));
typedef f16  f16x4 __attribute__((ext_vector_type(4)));
typedef float f32x4 __attribute__((ext_vector_type(4)));
typedef unsigned u32x4 __attribute__((ext_vector_type(4)));

#define L2E 1.44269504f

// ---------------- fused preprocessing: conv_x | conv_w | adj bitmask ----------------
// blocks 0..511: x->f16; 512..703: w->wB; 704..2751: adj->bitmask
__global__ void k_pre(const float* __restrict__ x, f16* __restrict__ x16a,
                      const float* __restrict__ w1, const float* __restrict__ w2,
                      const float* __restrict__ w3, f16* __restrict__ wB,
                      const float* __restrict__ adj, unsigned* __restrict__ am){
  int bid = blockIdx.x, t = threadIdx.x;
  if (bid < 512){
    int i = (bid*256 + t)*8;
    float4 a = *(const float4*)(x+i), b = *(const float4*)(x+i+4);
    f16x8 v;
    v[0]=(f16)a.x; v[1]=(f16)a.y; v[2]=(f16)a.z; v[3]=(f16)a.w;
    v[4]=(f16)b.x; v[5]=(f16)b.y; v[6]=(f16)b.z; v[7]=(f16)b.w;
    *(f16x8*)(x16a+i) = v;
  } else if (bid < 704){
    int e = (bid-512)*256 + t;                 // 49152 total
    int fc = e & 15, c = (e>>4)&127, h = (e>>11)&7, l = e>>14;
    const float* w = (l==0) ? w1 : ((l==1) ? w2 : w3);
    f16x8 v;
    #pragma unroll
    for(int j=0;j<8;j++) v[j] = (f16)w[(h*128 + fc*8 + j)*128 + c];
    *(f16x8*)(wB + (((l*8+h)*16 + fc)*128 + c)*8) = v;
  } else {
    int wv = t >> 6, lane = t & 63;
    int r = (bid-704)*4 + wv;                  // 0..8191
    const float* row = adj + (long)r*1024;
    for(int g=0; g<16; g++){
      float v = row[g*64 + lane];
      unsigned long long mb = __ballot(v > 0.0f);
      if (lane == 0){
        am[r*32 + 2*g]   = (unsigned)mb;
        am[r*32 + 2*g+1] = (unsigned)(mb >> 32);
      }
    }
  }
}

// ---------------- hp GEMM: hp = x @ w  (+tanh -> s,d) ----------------
// grid: 512 blocks, 256 threads.  bid decode: h = bid&7 so XCD(bid%8)==h.
// hpB layout: [b][h][jc=node/8][c][8]
__global__ __launch_bounds__(256,2) void k_hp(
    const f16* __restrict__ xin,      // [B][N][128] f16
    const f16* __restrict__ wBl,      // [H][16][128][8]
    const float* __restrict__ asrc, const float* __restrict__ adst,  // [H][128]
    f16* __restrict__ hpB,            // [B][H][128][128][8]
    float* __restrict__ sarr, float* __restrict__ darr)              // [B][H][1024]
{
  __shared__ f16 xs[128*136];     // x tile, later reused as tanh tile
  __shared__ float asl[128], adl[128];
  int t = threadIdx.x;
  int bid = blockIdx.x;
  int h = bid & 7, it = (bid>>3)&7, b = bid>>6;   // XCD affinity: bid%8 == h
  int i0 = it*128;
  {
    const f16* src = xin + (long)(b*1024 + i0)*128;
    int fc = t & 15, r0 = t >> 4;
    #pragma unroll
    for(int p=0;p<8;p++){
      int r = r0 + p*16;
      f16x8 v = *(const f16x8*)(src + r*128 + fc*8);
      *(f16x8*)(xs + r*136 + fc*8) = v;
    }
  }
  if (t < 128){ asl[t] = asrc[h*128+t]; adl[t] = adst[h*128+t]; }
  __syncthreads();

  int lane = t & 63, wv = t>>6, wr = wv>>1, wc = wv&1;
  int mq = lane & 15, quad = lane >> 4;
  f32x4 acc[4][4];
  #pragma unroll
  for(int a=0;a<4;a++)
    #pragma unroll
    for(int c=0;c<4;c++) acc[a][c] = (f32x4){0.f,0.f,0.f,0.f};

  const f16* wh = wBl + h*16*128*8;
  #pragma unroll
  for(int ks=0; ks<4; ks++){
    f16x8 af[4], bf[4];
    #pragma unroll
    for(int mt=0; mt<4; mt++)
      af[mt] = *(const f16x8*)(xs + (wr*64 + mt*16 + mq)*136 + ks*32 + quad*8);
    #pragma unroll
    for(int nt=0; nt<4; nt++){
      int c  = wc*64 + nt*16 + mq;
      int fc = ks*4 + quad;
      bf[nt] = *(const f16x8*)(wh + (fc*128 + c)*8);
    }
    #pragma unroll
    for(int mt=0; mt<4; mt++)
      #pragma unroll
      for(int nt=0; nt<4; nt++)
        acc[mt][nt] = __builtin_amdgcn_mfma_f32_16x16x32_f16(af[mt], bf[nt], acc[mt][nt], 0,0,0);
  }
  __syncthreads();          // xs dead -> reuse as tanh tile
  f16* tt = xs;             // [128][136]
  f16* hpb = hpB + (long)(b*8+h)*128*128*8;
  #pragma unroll
  for(int mt=0; mt<4; mt++){
    #pragma unroll
    for(int nt=0; nt<4; nt++){
      int c = wc*64 + nt*16 + mq;
      f16x4 pk;
      #pragma unroll
      for(int rg=0; rg<4; rg++){
        float v = acc[mt][nt][rg];
        pk[rg] = (f16)v;
        int il = wr*64 + mt*16 + quad*4 + rg;    // 0..127
        float e2 = __expf(2.0f*v);
        float th = 1.0f - 2.0f*__builtin_amdgcn_rcpf(e2 + 1.0f);
        tt[il*136 + c] = (f16)th;
      }
      int il0 = wr*64 + mt*16 + quad*4;
      int inode = i0 + il0;
      *(f16x4*)(hpb + ((long)(inode>>3)*128 + c)*8 + (inode&7)) = pk;  // 8B packed store
    }
  }
  __syncthreads();
  {
    int r = t>>1, hf = t&1;
    float s_p = 0.f, d_p = 0.f;
    #pragma unroll
    for(int q=0;q<8;q++){
      f16x8 tv = *(const f16x8*)(tt + r*136 + hf*64 + q*8);
      #pragma unroll
      for(int j=0;j<8;j++){
        float tvf = (float)tv[j];
        int c = hf*64 + q*8 + j;
        s_p = fmaf(tvf, asl[c], s_p);
        d_p = fmaf(tvf, adl[c], d_p);
      }
    }
    s_p += __shfl_xor(s_p, 1);
    d_p += __shfl_xor(d_p, 1);
    if (hf == 0){
      sarr[(b*8+h)*1024 + i0 + r] = s_p;
      darr[(b*8+h)*1024 + i0 + r] = d_p;
    }
  }
}

// ---------------- attention (row-split, P built IN REGISTERS, barrier-free main loop) ----------------
// grid: 1024 blocks: bid = it*64 + bh  (same-bh blocks -> XCD bh%8 == h, matching k_hp)
// R8: the R5 structure saturated the per-CU LDS pipe: 16 waves x 8 ds_read_b128
// (every wave re-read the whole shared P tile) + P stores + dloc reads ~ 2600 cy/phase.
// Now lane (mq,quad) computes the exps for exactly the A-fragment elements it feeds
// to MFMA -- P[mt*16+mq][kk*32+quad*8+j] -- and inserts them into zeroed u32x4 frags
// via cndmask (static mt/kk indexing, no scratch).  P never touches LDS: no P stores,
// no A-frag LDS reads, NO main-loop barriers (nothing cross-thread).  z reduces via
// shfl_xor(16/32).  d-loads stay batched (R4 win); masks prefetched as per-row uint2
// on the VMEM pipe (double-buffered); B frags single-buffered (loads covered by the
// next phase's PFILL VALU + free-running waves).
__global__ __launch_bounds__(256,4) void k_attn(
    const f16* __restrict__ hpB,      // [B*H][128][128][8]  (jc, c, e)
    const float* __restrict__ sarr, const float* __restrict__ darr,
    const unsigned* __restrict__ am,  // [B*1024][32]
    f16* __restrict__ part)           // [64][1024][128] f16, normalized * 0.125
{
  __shared__ float ddl[1024];         // log2e-scaled d, all columns (read-only after prologue)
  __shared__ float wred[4];
  __shared__ f16 Ps[64*136];          // epilogue transpose only
  int t = threadIdx.x;
  int bid = blockIdx.x;
  int bh = bid & 63, it = bid >> 6;
  int i0 = it*64;
  int b = bh >> 3;

  int lane = t&63, wv = t>>6;
  int mq = lane&15, quad = lane>>4;
  const f16* hpb = hpB + (long)bh*128*128*8;

  // stage scaled d (all 1024) + global max of d
  {
    float4 v = *(const float4*)(darr + bh*1024 + t*4);
    float mx = fmaxf(fmaxf(v.x,v.y), fmaxf(v.z,v.w));
    #pragma unroll
    for(int o=1;o<64;o<<=1) mx = fmaxf(mx, __shfl_xor(mx, o));
    if (lane == 0) wred[wv] = mx;
    *(float4*)(ddl + t*4) = make_float4(v.x*L2E, v.y*L2E, v.z*L2E, v.w*L2E);
  }

  // this lane owns rows  r[mt] = i0 + mt*16 + mq  (the A-frag rows of its wave)
  const unsigned* amq = am + ((long)(b*1024 + i0 + mq))*32;

  // prefetch mask uint2 for tiles 0/1 (per owned row) + B frags for tile 0
  uint2 mA[4], mB[4];
  #pragma unroll
  for(int mt=0;mt<4;mt++){
    const unsigned* ar = amq + mt*512;
    mA[mt] = *(const uint2*)(ar);
    mB[mt] = *(const uint2*)(ar + 2);
  }
  f16x8 bf[4];
  #pragma unroll
  for(int kk=0;kk<2;kk++)
    #pragma unroll
    for(int nt=0;nt<2;nt++){
      int c  = wv*32 + nt*16 + mq;
      int jc = kk*4 + quad;
      bf[kk*2+nt] = *(const f16x8*)(hpb + ((long)jc*128 + c)*8);
    }

  __syncthreads();
  float Dml = fmaxf(fmaxf(wred[0],wred[1]), fmaxf(wred[2],wred[3])) * L2E;
  float srl[4], mrl[4];
  #pragma unroll
  for(int mt=0;mt<4;mt++){
    float s = sarr[bh*1024 + i0 + mt*16 + mq] * L2E;
    srl[mt] = s;
    float ml = s + Dml;
    mrl[mt] = fmaxf(ml, 0.2f*ml);   // log2-domain upper bound of masked scores
  }

  f32x4 acc[4][2];
  #pragma unroll
  for(int a=0;a<4;a++){ acc[a][0] = (f32x4){0.f,0.f,0.f,0.f}; acc[a][1] = (f32x4){0.f,0.f,0.f,0.f}; }
  float zac[4] = {0.f,0.f,0.f,0.f};
  const u32x4 zero4 = (u32x4){0u,0u,0u,0u};
  int sh8 = quad*8;

  // insert f16(E) at combined col-slot J (0..15) of row mt's frag pair (dwords 0..7)
#define INS(MT, J, E) {                                                        \
    unsigned hu = (unsigned)__builtin_bit_cast(unsigned short,(f16)(E))        \
                  << (((J)&1)*16);                                             \
    int dw = (J)>>1;                                                           \
    a0[MT][0] |= (dw==0)?hu:0u; a0[MT][1] |= (dw==1)?hu:0u;                    \
    a0[MT][2] |= (dw==2)?hu:0u; a0[MT][3] |= (dw==3)?hu:0u;                    \
    a1[MT][0] |= (dw==4)?hu:0u; a1[MT][1] |= (dw==5)?hu:0u;                    \
    a1[MT][2] |= (dw==6)?hu:0u; a1[MT][3] |= (dw==7)?hu:0u; }

  for(int jt=0; jt<16; jt++){
    // ---- build A-frags in registers (sparse, batched d-loads per row) ----
    u32x4 a0[4], a1[4];
    #pragma unroll
    for(int mt=0;mt<4;mt++){ a0[mt]=zero4; a1[mt]=zero4; }
    const float* dl = ddl + jt*64 + sh8;
    #pragma unroll
    for(int mt=0;mt<4;mt++){
      unsigned w16 = ((mA[mt].x >> sh8) & 0xffu) | (((mA[mt].y >> sh8) & 0xffu) << 8);
      if (w16){
        int n = __popc(w16);
        unsigned w = w16;
        int j0 = __builtin_ctz(w); w &= w-1u;
        int j1 = w ? __builtin_ctz(w) : j0; w = w ? (w & (w-1u)) : 0u;
        int j2 = w ? __builtin_ctz(w) : j0; w = w ? (w & (w-1u)) : 0u;
        int j3 = w ? __builtin_ctz(w) : j0;
        unsigned wrest = w ? (w & (w-1u)) : 0u;
        int o0 = (j0&7) + ((j0>>3)<<5), o1 = (j1&7) + ((j1>>3)<<5);
        int o2 = (j2&7) + ((j2>>3)<<5), o3 = (j3&7) + ((j3>>3)<<5);
        float d0 = dl[o0], d1 = dl[o1], d2 = dl[o2], d3 = dl[o3];
        float x0 = srl[mt]+d0, x1 = srl[mt]+d1, x2 = srl[mt]+d2, x3 = srl[mt]+d3;
        float e0 = __builtin_amdgcn_exp2f(fmaxf(x0,0.2f*x0) - mrl[mt]);
        float e1 = __builtin_amdgcn_exp2f(fmaxf(x1,0.2f*x1) - mrl[mt]);
        float e2 = __builtin_amdgcn_exp2f(fmaxf(x2,0.2f*x2) - mrl[mt]);
        float e3 = __builtin_amdgcn_exp2f(fmaxf(x3,0.2f*x3) - mrl[mt]);
        zac[mt] += e0; INS(mt, j0, e0)
        if (n > 1){ zac[mt] += e1; INS(mt, j1, e1) }
        if (n > 2){ zac[mt] += e2; INS(mt, j2, e2) }
        if (n > 3){ zac[mt] += e3; INS(mt, j3, e3) }
        while (wrest){
          int j = __builtin_ctz(wrest); wrest &= wrest-1u;
          int o = (j&7) + ((j>>3)<<5);
          float xl = srl[mt] + dl[o];
          float e  = __builtin_amdgcn_exp2f(fmaxf(xl,0.2f*xl) - mrl[mt]);
          zac[mt] += e; INS(mt, j, e)
        }
      }
    }
    // ---- MFMA (A from regs, B from regs) ----
    #pragma unroll
    for(int kk=0;kk<2;kk++){
      #pragma unroll
      for(int mt=0;mt<4;mt++){
        f16x8 a = __builtin_bit_cast(f16x8, kk ? a1[mt] : a0[mt]);
        #pragma unroll
        for(int nt=0;nt<2;nt++)
          acc[mt][nt] = __builtin_amdgcn_mfma_f32_16x16x32_f16(a, bf[kk*2+nt], acc[mt][nt], 0,0,0);
      }
    }
    // ---- rotate masks, prefetch next masks + B frags (no barriers anywhere) ----
    #pragma unroll
    for(int mt=0;mt<4;mt++) mA[mt] = mB[mt];
    if (jt < 14){
      #pragma unroll
      for(int mt=0;mt<4;mt++)
        mB[mt] = *(const uint2*)(amq + mt*512 + (jt+2)*2);
    }
    if (jt < 15){
      #pragma unroll
      for(int kk=0;kk<2;kk++)
        #pragma unroll
        for(int nt=0;nt<2;nt++){
          int c  = wv*32 + nt*16 + mq;
          int jc = (jt+1)*8 + kk*4 + quad;
          bf[kk*2+nt] = *(const f16x8*)(hpb + ((long)jc*128 + c)*8);
        }
    }
  }
#undef INS

  // full softmax denominator per owned row: reduce across the quad group
  #pragma unroll
  for(int mt=0;mt<4;mt++){
    zac[mt] += __shfl_xor(zac[mt], 16);
    zac[mt] += __shfl_xor(zac[mt], 32);
  }

  // normalize + head-prescale, transpose through LDS for coalesced f16x8 stores
  // acc element (mt,nt,rg): row = mt*16 + quad*4 + rg, chan = wv*32 + nt*16 + mq.
  // z for that row lives at lane (quad*4+rg) (its mq == row index), post-reduce.
  #pragma unroll
  for(int mt=0;mt<4;mt++){
    #pragma unroll
    for(int rg=0;rg<4;rg++){
      float zr = __shfl(zac[mt], quad*4 + rg);
      float zi = 0.125f * __builtin_amdgcn_rcpf(zr);
      int il = mt*16 + quad*4 + rg;
      #pragma unroll
      for(int nt=0;nt<2;nt++){
        int c = wv*32 + nt*16 + mq;
        Ps[il*136 + c] = (f16)(acc[mt][nt][rg] * zi);
      }
    }
  }
  __syncthreads();
  {
    int r = t>>2, g = t&3;
    f16* dst = part + ((long)bh*1024 + i0 + r)*128 + g*32;
    const f16* srcp = Ps + r*136 + g*32;
    *(f16x8*)(dst)    = *(const f16x8*)(srcp);
    *(f16x8*)(dst+8)  = *(const f16x8*)(srcp+8);
    *(f16x8*)(dst+16) = *(const f16x8*)(srcp+16);
    *(f16x8*)(dst+24) = *(const f16x8*)(srcp+24);
  }
}

// ---------------- finalize: sum heads (already normalized+prescaled), bias(+relu), partial node-max ----------------
// 512 blocks x 256: block covers one b, 16 nodes, all 128 channels
__global__ void k_fin(const f16* __restrict__ part, const float* __restrict__ bias,
                      f16* __restrict__ x16, float* __restrict__ pmax, int do_relu){
  __shared__ float pm[16][128];
  int t = threadIdx.x;
  int idx = blockIdx.x*256 + t;   // b(3)|n(10)|c8(4)
  int c8 = idx & 15, n = (idx>>4)&1023, b = idx>>14;
  float s[8];
  #pragma unroll
  for(int j=0;j<8;j++) s[j] = 0.f;
  #pragma unroll
  for(int h=0;h<8;h++){
    int bh = b*8 + h;
    f16x8 p0 = *(const f16x8*)(part + ((long)bh*1024 + n)*128 + c8*8);
    #pragma unroll
    for(int j=0;j<8;j++) s[j] += (float)p0[j];
  }
  f16x8 h8;
  float ov[8];
  #pragma unroll
  for(int j=0;j<8;j++){
    float v = s[j] + bias[c8*8 + j];
    if (do_relu) v = fmaxf(v, 0.f);
    ov[j] = v;
    h8[j] = (f16)v;
  }
  if (x16) *(f16x8*)(x16 + ((long)(b*1024+n))*128 + c8*8) = h8;
  #pragma unroll
  for(int j=0;j<8;j++) pm[n&15][c8*8+j] = ov[j];
  __syncthreads();
  if (t < 128){
    float m = pm[0][t];
    #pragma unroll
    for(int r=1;r<16;r++) m = fmaxf(m, pm[r][t]);
    pmax[blockIdx.x*128 + t] = m;   // [b*64+chunk][128]
  }
}

// ---------------- final: max over chunks + predictor ----------------
// 8 blocks x 256.  Coalesced chunk-max: lanes read consecutive channels (256B/wave);
// two half-partials combined in LDS.
__global__ void k_pool2(const float* __restrict__ pmax, const float* __restrict__ pw,
                        const float* __restrict__ pb, float* __restrict__ out){
  __shared__ float ph[2][384];
  __shared__ float pl[384];
  int b = blockIdx.x, t = threadIdx.x;
  int c = t & 127, half = t >> 7;
  #pragma unroll
  for(int l=0;l<3;l++){
    const float* p = pmax + l*65536 + b*8192 + half*32*128 + c;
    float m = -3.4e38f;
    #pragma unroll 8
    for(int kk=0;kk<32;kk++) m = fmaxf(m, p[kk*128]);
    ph[half][l*128 + c] = m;
  }
  __syncthreads();
  for(int f = t; f < 384; f += 256) pl[f] = fmaxf(ph[0][f], ph[1][f]);
  __syncthreads();
  if (t < 64){
    float a0 = 0.f, a1 = 0.f;
    #pragma unroll
    for(int k=0;k<6;k++){
      int f = t + 64*k;
      float v = pl[f];
      a0 = fmaf(v, pw[f*2],   a0);
      a1 = fmaf(v, pw[f*2+1], a1);
    }
    #pragma unroll
    for(int o=1;o<64;o<<=1){ a0 += __shfl_xor(a0,o); a1 += __shfl_xor(a1,o); }
    if (t == 0){ out[b*2] = a0 + pb[0]; out[b*2+1] = a1 + pb[1]; }
  }
}

// ---------------- launcher ----------------
extern "C" void kernel_launch(void* const* d_in, const int* in_sizes, int n_in,
                              void* d_out, int out_size, void* d_ws, size_t ws_size,
                              hipStream_t stream) {
  const float* x   = (const float*)d_in[0];
  const float* adj = (const float*)d_in[1];
  const float* w1  = (const float*)d_in[2];
  const float* as1 = (const float*)d_in[3];
  const float* ad1 = (const float*)d_in[4];
  const float* b1  = (const float*)d_in[5];
  const float* w2  = (const float*)d_in[6];
  const float* as2 = (const float*)d_in[7];
  const float* ad2 = (const float*)d_in[8];
  const float* b2  = (const float*)d_in[9];
  const float* w3  = (const float*)d_in[10];
  const float* as3 = (const float*)d_in[11];
  const float* ad3 = (const float*)d_in[12];
  const float* b3  = (const float*)d_in[13];
  const float* pw  = (const float*)d_in[14];
  const float* pb  = (const float*)d_in[15];

  char* ws = (char*)d_ws;
  f16*      x16a = (f16*)ws;                 ws += (size_t)1048576*2;
  f16*      x16b = (f16*)ws;                 ws += (size_t)1048576*2;
  f16*      wB   = (f16*)ws;                 ws += (size_t)393216*2;
  unsigned* am   = (unsigned*)ws;            ws += (size_t)8*1024*32*4;
  f16*      hpB  = (f16*)ws;                 ws += (size_t)8*8*1024*128*2;
  float*    sarr = (float*)ws;               ws += (size_t)65536*4;
  float*    darr = (float*)ws;               ws += (size_t)65536*4;
  f16*      part = (f16*)ws;                 ws += (size_t)64*1024*128*2;
  float*    pmax = (float*)ws;               ws += (size_t)3*512*128*4;

  k_pre<<<2752, 256, 0, stream>>>(x, x16a, w1, w2, w3, wB, adj, am);

  // layer 1
  k_hp  <<<512, 256, 0, stream>>>(x16a, wB,            as1, ad1, hpB, sarr, darr);
  k_attn<<<1024,256, 0, stream>>>(hpB, sarr, darr, am, part);
  k_fin <<<512, 256, 0, stream>>>(part, b1, x16b, pmax,           1);
  // layer 2
  k_hp  <<<512, 256, 0, stream>>>(x16b, wB + 131072,   as2, ad2, hpB, sarr, darr);
  k_attn<<<1024,256, 0, stream>>>(hpB, sarr, darr, am, part);
  k_fin <<<512, 256, 0, stream>>>(part, b2, x16a, pmax + 65536,   1);
  // layer 3
  k_hp  <<<512, 256, 0, stream>>>(x16a, wB + 262144,   as3, ad3, hpB, sarr, darr);
  k_attn<<<1024,256, 0, stream>>>(hpB, sarr, darr, am, part);
  k_fin <<<512, 256, 0, stream>>>(part, b3, nullptr, pmax + 131072, 0);

  k_pool2<<<8, 256, 0, stream>>>(pmax, pw, pb, (float*)d_out);
}

// Round 9
// 267.798 us; speedup vs baseline: 1.5733x; 1.5733x over previous
//
#include <hip/hip_runtime.h>
#include <hip/hip_fp16.h>

#define BB 8
#define NN 1024
#define FF 128
#define HH 8

typedef _Float16 f16;
typedef f16  f16x8 __attribute__((ext_vector_type(8)));
typedef f16  f16x4 __attribute__((ext_vector_type(4)));
typedef float f32x4 __attribute__((ext_vector_type(4)));

#define L2E 1.44269504f

// ---------------- fused preprocessing: conv_x | conv_w | adj bitmask ----------------
// blocks 0..511: x->f16; 512..703: w->wB; 704..2751: adj->bitmask
__global__ void k_pre(const float* __restrict__ x, f16* __restrict__ x16a,
                      const float* __restrict__ w1, const float* __restrict__ w2,
                      const float* __restrict__ w3, f16* __restrict__ wB,
                      const float* __restrict__ adj, unsigned* __restrict__ am){
  int bid = blockIdx.x, t = threadIdx.x;
  if (bid < 512){
    int i = (bid*256 + t)*8;
    float4 a = *(const float4*)(x+i), b = *(const float4*)(x+i+4);
    f16x8 v;
    v[0]=(f16)a.x; v[1]=(f16)a.y; v[2]=(f16)a.z; v[3]=(f16)a.w;
    v[4]=(f16)b.x; v[5]=(f16)b.y; v[6]=(f16)b.z; v[7]=(f16)b.w;
    *(f16x8*)(x16a+i) = v;
  } else if (bid < 704){
    int e = (bid-512)*256 + t;                 // 49152 total
    int fc = e & 15, c = (e>>4)&127, h = (e>>11)&7, l = e>>14;
    const float* w = (l==0) ? w1 : ((l==1) ? w2 : w3);
    f16x8 v;
    #pragma unroll
    for(int j=0;j<8;j++) v[j] = (f16)w[(h*128 + fc*8 + j)*128 + c];
    *(f16x8*)(wB + (((l*8+h)*16 + fc)*128 + c)*8) = v;
  } else {
    int wv = t >> 6, lane = t & 63;
    int r = (bid-704)*4 + wv;                  // 0..8191
    const float* row = adj + (long)r*1024;
    for(int g=0; g<16; g++){
      float v = row[g*64 + lane];
      unsigned long long mb = __ballot(v > 0.0f);
      if (lane == 0){
        am[r*32 + 2*g]   = (unsigned)mb;
        am[r*32 + 2*g+1] = (unsigned)(mb >> 32);
      }
    }
  }
}

// ---------------- hp GEMM layer 1: hp = x @ w  (+tanh -> s,d) ----------------
// grid: 512 blocks, 256 threads.  h = bid&7 so XCD(bid%8)==h.
// hpB layout: [b][h][jc=node/8][c][8]
__global__ __launch_bounds__(256,2) void k_hp(
    const f16* __restrict__ xin,      // [B][N][128] f16
    const f16* __restrict__ wBl,      // [H][16][128][8]
    const float* __restrict__ asrc, const float* __restrict__ adst,  // [H][128]
    f16* __restrict__ hpB,            // [B][H][128][128][8]
    float* __restrict__ sarr, float* __restrict__ darr)              // [B][H][1024]
{
  __shared__ f16 xs[128*136];     // x tile, later reused as tanh tile
  __shared__ float asl[128], adl[128];
  int t = threadIdx.x;
  int bid = blockIdx.x;
  int h = bid & 7, it = (bid>>3)&7, b = bid>>6;   // XCD affinity: bid%8 == h
  int i0 = it*128;
  {
    const f16* src = xin + (long)(b*1024 + i0)*128;
    int fc = t & 15, r0 = t >> 4;
    #pragma unroll
    for(int p=0;p<8;p++){
      int r = r0 + p*16;
      f16x8 v = *(const f16x8*)(src + r*128 + fc*8);
      *(f16x8*)(xs + r*136 + fc*8) = v;
    }
  }
  if (t < 128){ asl[t] = asrc[h*128+t]; adl[t] = adst[h*128+t]; }
  __syncthreads();

  int lane = t & 63, wv = t>>6, wr = wv>>1, wc = wv&1;
  int mq = lane & 15, quad = lane >> 4;
  f32x4 acc[4][4];
  #pragma unroll
  for(int a=0;a<4;a++)
    #pragma unroll
    for(int c=0;c<4;c++) acc[a][c] = (f32x4){0.f,0.f,0.f,0.f};

  const f16* wh = wBl + h*16*128*8;
  #pragma unroll
  for(int ks=0; ks<4; ks++){
    f16x8 af[4], bf[4];
    #pragma unroll
    for(int mt=0; mt<4; mt++)
      af[mt] = *(const f16x8*)(xs + (wr*64 + mt*16 + mq)*136 + ks*32 + quad*8);
    #pragma unroll
    for(int nt=0; nt<4; nt++){
      int c  = wc*64 + nt*16 + mq;
      int fc = ks*4 + quad;
      bf[nt] = *(const f16x8*)(wh + (fc*128 + c)*8);
    }
    #pragma unroll
    for(int mt=0; mt<4; mt++)
      #pragma unroll
      for(int nt=0; nt<4; nt++)
        acc[mt][nt] = __builtin_amdgcn_mfma_f32_16x16x32_f16(af[mt], bf[nt], acc[mt][nt], 0,0,0);
  }
  __syncthreads();          // xs dead -> reuse as tanh tile
  f16* tt = xs;             // [128][136]
  f16* hpb = hpB + (long)(b*8+h)*128*128*8;
  #pragma unroll
  for(int mt=0; mt<4; mt++){
    #pragma unroll
    for(int nt=0; nt<4; nt++){
      int c = wc*64 + nt*16 + mq;
      f16x4 pk;
      #pragma unroll
      for(int rg=0; rg<4; rg++){
        float v = acc[mt][nt][rg];
        pk[rg] = (f16)v;
        int il = wr*64 + mt*16 + quad*4 + rg;    // 0..127
        float e2 = __expf(2.0f*v);
        float th = 1.0f - 2.0f*__builtin_amdgcn_rcpf(e2 + 1.0f);
        tt[il*136 + c] = (f16)th;
      }
      int il0 = wr*64 + mt*16 + quad*4;
      int inode = i0 + il0;
      *(f16x4*)(hpb + ((long)(inode>>3)*128 + c)*8 + (inode&7)) = pk;  // 8B packed store
    }
  }
  __syncthreads();
  {
    int r = t>>1, hf = t&1;
    float s_p = 0.f, d_p = 0.f;
    #pragma unroll
    for(int q=0;q<8;q++){
      f16x8 tv = *(const f16x8*)(tt + r*136 + hf*64 + q*8);
      #pragma unroll
      for(int j=0;j<8;j++){
        float tvf = (float)tv[j];
        int c = hf*64 + q*8 + j;
        s_p = fmaf(tvf, asl[c], s_p);
        d_p = fmaf(tvf, adl[c], d_p);
      }
    }
    s_p += __shfl_xor(s_p, 1);
    d_p += __shfl_xor(d_p, 1);
    if (hf == 0){
      sarr[(b*8+h)*1024 + i0 + r] = s_p;
      darr[(b*8+h)*1024 + i0 + r] = d_p;
    }
  }
}

// ---------------- hp GEMM layers 2/3: fused k_fin prologue (head-sum from part) ----------------
// Replaces k_fin(layer l) + x16 round-trip: prologue builds the x tile directly from
// part (sum 8 heads + bias + relu), tracking the f32 node-max (pre-f16-rounding, same
// reduction order as old k_fin) which the h==0 block writes to pmaxl[b*8+it][128].
// ~256KB L2-resident part reads per block (8x redundancy across h-blocks ~ 4us total).
__global__ __launch_bounds__(256,2) void k_hpf(
    const f16* __restrict__ part,     // [64][1024][128] f16, normalized*0.125
    const float* __restrict__ biasp,  // bias of PREVIOUS layer (added before relu)
    const f16* __restrict__ wBl,
    const float* __restrict__ asrc, const float* __restrict__ adst,
    f16* __restrict__ hpB, float* __restrict__ sarr, float* __restrict__ darr,
    float* __restrict__ pmaxl)        // [64][128] chunk-max for previous layer output
{
  __shared__ f16 xs[128*136];
  __shared__ float asl[128], adl[128];
  __shared__ float pmf[16][128];
  int t = threadIdx.x;
  int bid = blockIdx.x;
  int h = bid & 7, it = (bid>>3)&7, b = bid>>6;
  int i0 = it*128;
  {
    int c8 = t & 15, rr = t >> 4;     // this thread: rows rr+p*16, chans c8*8..+7
    float bl[8], vmax[8];
    #pragma unroll
    for(int j=0;j<8;j++){ bl[j] = biasp[c8*8+j]; vmax[j] = -3.4e38f; }
    #pragma unroll
    for(int p=0;p<8;p++){
      int row = rr + p*16;
      float s[8];
      #pragma unroll
      for(int j=0;j<8;j++) s[j] = bl[j];
      #pragma unroll
      for(int hh=0;hh<8;hh++){
        f16x8 pv = *(const f16x8*)(part + ((long)(b*8+hh)*1024 + i0 + row)*128 + c8*8);
        #pragma unroll
        for(int j=0;j<8;j++) s[j] += (float)pv[j];
      }
      f16x8 o;
      #pragma unroll
      for(int j=0;j<8;j++){
        float v = fmaxf(s[j], 0.f);
        vmax[j] = fmaxf(vmax[j], v);
        o[j] = (f16)v;
      }
      *(f16x8*)(xs + row*136 + c8*8) = o;
    }
    if (h == 0){
      #pragma unroll
      for(int j=0;j<8;j++) pmf[rr][c8*8+j] = vmax[j];
    }
  }
  if (t < 128){ asl[t] = asrc[h*128+t]; adl[t] = adst[h*128+t]; }
  __syncthreads();
  if (h == 0 && t < 128){
    float m = pmf[0][t];
    #pragma unroll
    for(int r=1;r<16;r++) m = fmaxf(m, pmf[r][t]);
    pmaxl[(b*8+it)*128 + t] = m;
  }

  int lane = t & 63, wv = t>>6, wr = wv>>1, wc = wv&1;
  int mq = lane & 15, quad = lane >> 4;
  f32x4 acc[4][4];
  #pragma unroll
  for(int a=0;a<4;a++)
    #pragma unroll
    for(int c=0;c<4;c++) acc[a][c] = (f32x4){0.f,0.f,0.f,0.f};

  const f16* wh = wBl + h*16*128*8;
  #pragma unroll
  for(int ks=0; ks<4; ks++){
    f16x8 af[4], bf[4];
    #pragma unroll
    for(int mt=0; mt<4; mt++)
      af[mt] = *(const f16x8*)(xs + (wr*64 + mt*16 + mq)*136 + ks*32 + quad*8);
    #pragma unroll
    for(int nt=0; nt<4; nt++){
      int c  = wc*64 + nt*16 + mq;
      int fc = ks*4 + quad;
      bf[nt] = *(const f16x8*)(wh + (fc*128 + c)*8);
    }
    #pragma unroll
    for(int mt=0; mt<4; mt++)
      #pragma unroll
      for(int nt=0; nt<4; nt++)
        acc[mt][nt] = __builtin_amdgcn_mfma_f32_16x16x32_f16(af[mt], bf[nt], acc[mt][nt], 0,0,0);
  }
  __syncthreads();          // xs dead -> reuse as tanh tile
  f16* tt = xs;             // [128][136]
  f16* hpb = hpB + (long)(b*8+h)*128*128*8;
  #pragma unroll
  for(int mt=0; mt<4; mt++){
    #pragma unroll
    for(int nt=0; nt<4; nt++){
      int c = wc*64 + nt*16 + mq;
      f16x4 pk;
      #pragma unroll
      for(int rg=0; rg<4; rg++){
        float v = acc[mt][nt][rg];
        pk[rg] = (f16)v;
        int il = wr*64 + mt*16 + quad*4 + rg;    // 0..127
        float e2 = __expf(2.0f*v);
        float th = 1.0f - 2.0f*__builtin_amdgcn_rcpf(e2 + 1.0f);
        tt[il*136 + c] = (f16)th;
      }
      int il0 = wr*64 + mt*16 + quad*4;
      int inode = i0 + il0;
      *(f16x4*)(hpb + ((long)(inode>>3)*128 + c)*8 + (inode&7)) = pk;  // 8B packed store
    }
  }
  __syncthreads();
  {
    int r = t>>1, hf = t&1;
    float s_p = 0.f, d_p = 0.f;
    #pragma unroll
    for(int q=0;q<8;q++){
      f16x8 tv = *(const f16x8*)(tt + r*136 + hf*64 + q*8);
      #pragma unroll
      for(int j=0;j<8;j++){
        float tvf = (float)tv[j];
        int c = hf*64 + q*8 + j;
        s_p = fmaf(tvf, asl[c], s_p);
        d_p = fmaf(tvf, adl[c], d_p);
      }
    }
    s_p += __shfl_xor(s_p, 1);
    d_p += __shfl_xor(d_p, 1);
    if (hf == 0){
      sarr[(b*8+h)*1024 + i0 + r] = s_p;
      darr[(b*8+h)*1024 + i0 + r] = d_p;
    }
  }
}

// ---------------- attention (R5 structure: batched sparse P-fill, depth-2 pipelined) ----------------
// grid: 1024 blocks: bid = it*64 + bh  (same-bh blocks -> XCD bh%8 == h, matching k_hp)
// Best-measured attn (R5, 248.9us total).  R6 non-draining barriers / R7 128-col
// phases / R8 register-P all regressed or were neutral -- P stays in LDS, built
// cooperatively once per block; __syncthreads barriers; depth-2 B prefetch, full unroll.
__global__ __launch_bounds__(256,4) void k_attn(
    const f16* __restrict__ hpB,      // [B*H][128][128][8]  (jc, c, e)
    const float* __restrict__ sarr, const float* __restrict__ darr,
    const unsigned* __restrict__ am,  // [B*1024][32]
    f16* __restrict__ part)           // [64][1024][128] f16, normalized * 0.125
{
  __shared__ float ddl[1024];         // log2e-scaled d, all columns
  __shared__ float wred[4];
  __shared__ float zl[64];
  __shared__ f16 Pl[2][64*72];        // P tiles, row stride 72 f16 (144B, 16B aligned)
  int t = threadIdx.x;
  int bid = blockIdx.x;
  int bh = bid & 63, it = bid >> 6;
  int i0 = it*64;
  int b = bh >> 3;

  int lane = t&63, wv = t>>6;
  int mq = lane&15, quad = lane>>4;
  const f16* hpb = hpB + (long)bh*128*128*8;

  // stage scaled d (all 1024) + global max of d
  {
    float4 v = *(const float4*)(darr + bh*1024 + t*4);
    float mx = fmaxf(fmaxf(v.x,v.y), fmaxf(v.z,v.w));
    #pragma unroll
    for(int o=1;o<64;o<<=1) mx = fmaxf(mx, __shfl_xor(mx, o));
    if (lane == 0) wred[wv] = mx;
    *(float4*)(ddl + t*4) = make_float4(v.x*L2E, v.y*L2E, v.z*L2E, v.w*L2E);
  }

  int prow = t>>2, pg = t&3;          // row 0..63, 16-col group 0..3
  float srowl = sarr[bh*1024 + i0 + prow] * L2E;
  const unsigned* amrow = am + ((long)(b*1024 + i0 + prow))*32;
  int wsel = pg >> 1, wsh = (pg&1)*16;

  // prefetch B fragments for tiles 0 and 1 + mask words for tiles 0/1 (no LDS dep yet)
  f16x8 bf[3][4];
  #pragma unroll
  for(int kk=0;kk<2;kk++)
    #pragma unroll
    for(int nt=0;nt<2;nt++){
      int c  = wv*32 + nt*16 + mq;
      bf[0][kk*2+nt] = *(const f16x8*)(hpb + ((long)(kk*4 + quad)*128 + c)*8);
      bf[1][kk*2+nt] = *(const f16x8*)(hpb + ((long)(8 + kk*4 + quad)*128 + c)*8);
    }
  unsigned wcur = amrow[wsel];
  unsigned wnx  = amrow[2 + wsel];

  __syncthreads();
  float Dml = fmaxf(fmaxf(wred[0],wred[1]), fmaxf(wred[2],wred[3])) * L2E;
  float ml = srowl + Dml;
  float mrowl = fmaxf(ml, 0.2f*ml);   // log2-domain upper bound of masked scores

  f32x4 acc[4][2];
  #pragma unroll
  for(int a=0;a<4;a++){ acc[a][0] = (f32x4){0.f,0.f,0.f,0.f}; acc[a][1] = (f32x4){0.f,0.f,0.f,0.f}; }
  float zacc = 0.f;
  f16x8 zerov = (f16x8){0,0,0,0,0,0,0,0};

  // batched sparse P-fill (R4): ctz-chain extracts up to 4 indices, the 4 LDS loads
  // issue together (one ~120cy latency), rare >4-bit fallback loop
#define PFILL(BUF, WORDSRC, DBASE)                                        \
  {                                                                       \
    f16* myp = Pl[BUF] + prow*72 + pg*16;                                 \
    *(f16x8*)myp = zerov; *(f16x8*)(myp+8) = zerov;                       \
    unsigned word = ((WORDSRC) >> wsh) & 0xffffu;                         \
    const float* dloc = ddl + (DBASE) + pg*16;                            \
    if (word){                                                            \
      int n = __popc(word);                                               \
      unsigned w = word;                                                  \
      int j0 = __builtin_ctz(w); w &= w-1u;                               \
      int j1 = w ? __builtin_ctz(w) : j0; w = w ? (w & (w-1u)) : 0u;      \
      int j2 = w ? __builtin_ctz(w) : j0; w = w ? (w & (w-1u)) : 0u;      \
      int j3 = w ? __builtin_ctz(w) : j0;                                 \
      unsigned wrest = w ? (w & (w-1u)) : 0u;                             \
      float v0 = dloc[j0], v1 = dloc[j1], v2 = dloc[j2], v3 = dloc[j3];   \
      float x0 = srowl+v0, x1 = srowl+v1, x2 = srowl+v2, x3 = srowl+v3;   \
      float e0 = __builtin_amdgcn_exp2f(fmaxf(x0,0.2f*x0) - mrowl);       \
      float e1 = __builtin_amdgcn_exp2f(fmaxf(x1,0.2f*x1) - mrowl);      \
      float e2 = __builtin_amdgcn_exp2f(fmaxf(x2,0.2f*x2) - mrowl);      \
      float e3 = __builtin_amdgcn_exp2f(fmaxf(x3,0.2f*x3) - mrowl);      \
      zacc += e0; myp[j0] = (f16)e0;                                      \
      if (n > 1){ zacc += e1; myp[j1] = (f16)e1; }                        \
      if (n > 2){ zacc += e2; myp[j2] = (f16)e2; }                        \
      if (n > 3){ zacc += e3; myp[j3] = (f16)e3; }                        \
      while (wrest){                                                      \
        int j = __builtin_ctz(wrest); wrest &= wrest-1u;                  \
        float xl = srowl + dloc[j];                                       \
        float e  = __builtin_amdgcn_exp2f(fmaxf(xl,0.2f*xl) - mrowl);     \
        zacc += e; myp[j] = (f16)e;                                       \
      }                                                                   \
    }                                                                     \
  }

  PFILL(0, wcur, 0)
  __syncthreads();

  #pragma unroll
  for(int jt=0; jt<16; jt++){
    if (jt < 14){
      // issue B fragments for tile jt+2 (consumed two phases later)
      #pragma unroll
      for(int kk=0;kk<2;kk++)
        #pragma unroll
        for(int nt=0;nt<2;nt++){
          int c  = wv*32 + nt*16 + mq;
          int jc = (jt+2)*8 + kk*4 + quad;
          bf[(jt+2)%3][kk*2+nt] = *(const f16x8*)(hpb + ((long)jc*128 + c)*8);
        }
    }
    if (jt < 15){
      unsigned wfut = (jt < 14) ? amrow[(jt+2)*2 + wsel] : 0u;
      // fill tile jt+1 into the other buffer (disjoint from MFMA reads of tile jt)
      PFILL((jt+1)&1, wnx, (jt+1)*64)
      wnx = wfut;
    }
    const f16* Pc = Pl[jt&1];
    #pragma unroll
    for(int kk=0;kk<2;kk++){
      #pragma unroll
      for(int mt=0;mt<4;mt++){
        f16x8 a = *(const f16x8*)(Pc + (mt*16+mq)*72 + kk*32 + quad*8);
        #pragma unroll
        for(int nt=0;nt<2;nt++)
          acc[mt][nt] = __builtin_amdgcn_mfma_f32_16x16x32_f16(a, bf[jt%3][kk*2+nt], acc[mt][nt], 0,0,0);
      }
    }
    __syncthreads();
  }
#undef PFILL

  // full softmax denominator per row (4-lane group covers all 1024 cols)
  zacc += __shfl_xor(zacc, 1);
  zacc += __shfl_xor(zacc, 2);
  if (pg == 0) zl[prow] = zacc;
  __syncthreads();

  // normalize + head-prescale, transpose through LDS for coalesced f16x8 stores
  f16* Ps = (f16*)Pl;                  // [64][136] f16 (272B stride, 16B aligned)
  #pragma unroll
  for(int mt=0;mt<4;mt++){
    #pragma unroll
    for(int rg=0;rg<4;rg++){
      int il = mt*16 + quad*4 + rg;
      float zi = 0.125f * __builtin_amdgcn_rcpf(zl[il]);
      #pragma unroll
      for(int nt=0;nt<2;nt++){
        int c = wv*32 + nt*16 + mq;
        Ps[il*136 + c] = (f16)(acc[mt][nt][rg] * zi);
      }
    }
  }
  __syncthreads();
  {
    int r = t>>2, g = t&3;
    f16* dst = part + ((long)bh*1024 + i0 + r)*128 + g*32;
    const f16* srcp = Ps + r*136 + g*32;
    *(f16x8*)(dst)    = *(const f16x8*)(srcp);
    *(f16x8*)(dst+8)  = *(const f16x8*)(srcp+8);
    *(f16x8*)(dst+16) = *(const f16x8*)(srcp+16);
    *(f16x8*)(dst+24) = *(const f16x8*)(srcp+24);
  }
}

// ---------------- finalize (layer 3 only): sum heads, bias, partial node-max ----------------
// 512 blocks x 256: block covers one b, 16 nodes, all 128 channels
__global__ void k_fin(const f16* __restrict__ part, const float* __restrict__ bias,
                      f16* __restrict__ x16, float* __restrict__ pmax, int do_relu){
  __shared__ float pm[16][128];
  int t = threadIdx.x;
  int idx = blockIdx.x*256 + t;   // b(3)|n(10)|c8(4)
  int c8 = idx & 15, n = (idx>>4)&1023, b = idx>>14;
  float s[8];
  #pragma unroll
  for(int j=0;j<8;j++) s[j] = 0.f;
  #pragma unroll
  for(int h=0;h<8;h++){
    int bh = b*8 + h;
    f16x8 p0 = *(const f16x8*)(part + ((long)bh*1024 + n)*128 + c8*8);
    #pragma unroll
    for(int j=0;j<8;j++) s[j] += (float)p0[j];
  }
  f16x8 h8;
  float ov[8];
  #pragma unroll
  for(int j=0;j<8;j++){
    float v = s[j] + bias[c8*8 + j];
    if (do_relu) v = fmaxf(v, 0.f);
    ov[j] = v;
    h8[j] = (f16)v;
  }
  if (x16) *(f16x8*)(x16 + ((long)(b*1024+n))*128 + c8*8) = h8;
  #pragma unroll
  for(int j=0;j<8;j++) pm[n&15][c8*8+j] = ov[j];
  __syncthreads();
  if (t < 128){
    float m = pm[0][t];
    #pragma unroll
    for(int r=1;r<16;r++) m = fmaxf(m, pm[r][t]);
    pmax[blockIdx.x*128 + t] = m;   // [b*64+chunk][128]
  }
}

// ---------------- final: max over chunks + predictor ----------------
// 8 blocks x 256.  Layers 1/2 pmax: [64][128] (8 chunks/b from k_hpf);
// layer 3 pmax: [512][128] (64 chunks/b from k_fin).
__global__ void k_pool2(const float* __restrict__ pmax0, const float* __restrict__ pmax1,
                        const float* __restrict__ pmax2,
                        const float* __restrict__ pw, const float* __restrict__ pb,
                        float* __restrict__ out){
  __shared__ float pl[384];
  int b = blockIdx.x, t = threadIdx.x;
  for(int f = t; f < 384; f += 256){
    int l = f >> 7, c = f & 127;
    float mx = -3.4e38f;
    if (l < 2){
      const float* p = (l==0 ? pmax0 : pmax1) + b*8*128 + c;
      #pragma unroll
      for(int k=0;k<8;k++) mx = fmaxf(mx, p[k*128]);
    } else {
      const float* p = pmax2 + b*64*128 + c;
      #pragma unroll 8
      for(int k=0;k<64;k++) mx = fmaxf(mx, p[k*128]);
    }
    pl[f] = mx;
  }
  __syncthreads();
  if (t < 64){
    float a0 = 0.f, a1 = 0.f;
    #pragma unroll
    for(int k=0;k<6;k++){
      int f = t + 64*k;
      float v = pl[f];
      a0 = fmaf(v, pw[f*2],   a0);
      a1 = fmaf(v, pw[f*2+1], a1);
    }
    #pragma unroll
    for(int o=1;o<64;o<<=1){ a0 += __shfl_xor(a0,o); a1 += __shfl_xor(a1,o); }
    if (t == 0){ out[b*2] = a0 + pb[0]; out[b*2+1] = a1 + pb[1]; }
  }
}

// ---------------- launcher ----------------
extern "C" void kernel_launch(void* const* d_in, const int* in_sizes, int n_in,
                              void* d_out, int out_size, void* d_ws, size_t ws_size,
                              hipStream_t stream) {
  const float* x   = (const float*)d_in[0];
  const float* adj = (const float*)d_in[1];
  const float* w1  = (const float*)d_in[2];
  const float* as1 = (const float*)d_in[3];
  const float* ad1 = (const float*)d_in[4];
  const float* b1  = (const float*)d_in[5];
  const float* w2  = (const float*)d_in[6];
  const float* as2 = (const float*)d_in[7];
  const float* ad2 = (const float*)d_in[8];
  const float* b2  = (const float*)d_in[9];
  const float* w3  = (const float*)d_in[10];
  const float* as3 = (const float*)d_in[11];
  const float* ad3 = (const float*)d_in[12];
  const float* b3  = (const float*)d_in[13];
  const float* pw  = (const float*)d_in[14];
  const float* pb  = (const float*)d_in[15];

  char* ws = (char*)d_ws;
  f16*      x16a = (f16*)ws;                 ws += (size_t)1048576*2;
  f16*      wB   = (f16*)ws;                 ws += (size_t)393216*2;
  unsigned* am   = (unsigned*)ws;            ws += (size_t)8*1024*32*4;
  f16*      hpB  = (f16*)ws;                 ws += (size_t)8*8*1024*128*2;
  float*    sarr = (float*)ws;               ws += (size_t)65536*4;
  float*    darr = (float*)ws;               ws += (size_t)65536*4;
  f16*      part = (f16*)ws;                 ws += (size_t)64*1024*128*2;
  float*    pmax0= (float*)ws;               ws += (size_t)64*128*4;
  float*    pmax1= (float*)ws;               ws += (size_t)64*128*4;
  float*    pmax2= (float*)ws;               ws += (size_t)512*128*4;

  k_pre<<<2752, 256, 0, stream>>>(x, x16a, w1, w2, w3, wB, adj, am);

  // layer 1
  k_hp  <<<512, 256, 0, stream>>>(x16a, wB,            as1, ad1, hpB, sarr, darr);
  k_attn<<<1024,256, 0, stream>>>(hpB, sarr, darr, am, part);
  // layer 2 (k_fin of layer 1 fused into k_hpf prologue)
  k_hpf <<<512, 256, 0, stream>>>(part, b1, wB + 131072, as2, ad2, hpB, sarr, darr, pmax0);
  k_attn<<<1024,256, 0, stream>>>(hpB, sarr, darr, am, part);
  // layer 3 (k_fin of layer 2 fused)
  k_hpf <<<512, 256, 0, stream>>>(part, b2, wB + 262144, as3, ad3, hpB, sarr, darr, pmax1);
  k_attn<<<1024,256, 0, stream>>>(hpB, sarr, darr, am, part);
  k_fin <<<512, 256, 0, stream>>>(part, b3, nullptr, pmax2, 0);

  k_pool2<<<8, 256, 0, stream>>>(pmax0, pmax1, pmax2, pw, pb, (float*)d_out);
}

// Round 10
// 249.594 us; speedup vs baseline: 1.6881x; 1.0729x over previous
//
#include <hip/hip_runtime.h>
#include <hip/hip_fp16.h>

#define BB 8
#define NN 1024
#define FF 128
#define HH 8

typedef _Float16 f16;
typedef f16  f16x8 __attribute__((ext_vector_type(8)));
typedef f16  f16x4 __attribute__((ext_vector_type(4)));
typedef float f32x4 __attribute__((ext_vector_type(4)));

#define L2E 1.44269504f

// ---------------- fused preprocessing: conv_x | conv_w | adj bitmask ----------------
// blocks 0..511: x->f16; 512..703: w->wB; 704..2751: adj->bitmask
__global__ void k_pre(const float* __restrict__ x, f16* __restrict__ x16a,
                      const float* __restrict__ w1, const float* __restrict__ w2,
                      const float* __restrict__ w3, f16* __restrict__ wB,
                      const float* __restrict__ adj, unsigned* __restrict__ am){
  int bid = blockIdx.x, t = threadIdx.x;
  if (bid < 512){
    int i = (bid*256 + t)*8;
    float4 a = *(const float4*)(x+i), b = *(const float4*)(x+i+4);
    f16x8 v;
    v[0]=(f16)a.x; v[1]=(f16)a.y; v[2]=(f16)a.z; v[3]=(f16)a.w;
    v[4]=(f16)b.x; v[5]=(f16)b.y; v[6]=(f16)b.z; v[7]=(f16)b.w;
    *(f16x8*)(x16a+i) = v;
  } else if (bid < 704){
    int e = (bid-512)*256 + t;                 // 49152 total
    int fc = e & 15, c = (e>>4)&127, h = (e>>11)&7, l = e>>14;
    const float* w = (l==0) ? w1 : ((l==1) ? w2 : w3);
    f16x8 v;
    #pragma unroll
    for(int j=0;j<8;j++) v[j] = (f16)w[(h*128 + fc*8 + j)*128 + c];
    *(f16x8*)(wB + (((l*8+h)*16 + fc)*128 + c)*8) = v;
  } else {
    int wv = t >> 6, lane = t & 63;
    int r = (bid-704)*4 + wv;                  // 0..8191
    const float* row = adj + (long)r*1024;
    for(int g=0; g<16; g++){
      float v = row[g*64 + lane];
      unsigned long long mb = __ballot(v > 0.0f);
      if (lane == 0){
        am[r*32 + 2*g]   = (unsigned)mb;
        am[r*32 + 2*g+1] = (unsigned)(mb >> 32);
      }
    }
  }
}

// ---------------- hp GEMM: hp = x @ w  (+tanh -> s,d) ----------------
// grid: 512 blocks, 256 threads.  h = bid&7 so XCD(bid%8)==h.
// hpB layout: [b][h][jc=node/8][c][8]
__global__ __launch_bounds__(256,2) void k_hp(
    const f16* __restrict__ xin,      // [B][N][128] f16
    const f16* __restrict__ wBl,      // [H][16][128][8]
    const float* __restrict__ asrc, const float* __restrict__ adst,  // [H][128]
    f16* __restrict__ hpB,            // [B][H][128][128][8]
    float* __restrict__ sarr, float* __restrict__ darr)              // [B][H][1024]
{
  __shared__ f16 xs[128*136];     // x tile, later reused as tanh tile
  __shared__ float asl[128], adl[128];
  int t = threadIdx.x;
  int bid = blockIdx.x;
  int h = bid & 7, it = (bid>>3)&7, b = bid>>6;   // XCD affinity: bid%8 == h
  int i0 = it*128;
  {
    const f16* src = xin + (long)(b*1024 + i0)*128;
    int fc = t & 15, r0 = t >> 4;
    #pragma unroll
    for(int p=0;p<8;p++){
      int r = r0 + p*16;
      f16x8 v = *(const f16x8*)(src + r*128 + fc*8);
      *(f16x8*)(xs + r*136 + fc*8) = v;
    }
  }
  if (t < 128){ asl[t] = asrc[h*128+t]; adl[t] = adst[h*128+t]; }
  __syncthreads();

  int lane = t & 63, wv = t>>6, wr = wv>>1, wc = wv&1;
  int mq = lane & 15, quad = lane >> 4;
  f32x4 acc[4][4];
  #pragma unroll
  for(int a=0;a<4;a++)
    #pragma unroll
    for(int c=0;c<4;c++) acc[a][c] = (f32x4){0.f,0.f,0.f,0.f};

  const f16* wh = wBl + h*16*128*8;
  #pragma unroll
  for(int ks=0; ks<4; ks++){
    f16x8 af[4], bf[4];
    #pragma unroll
    for(int mt=0; mt<4; mt++)
      af[mt] = *(const f16x8*)(xs + (wr*64 + mt*16 + mq)*136 + ks*32 + quad*8);
    #pragma unroll
    for(int nt=0; nt<4; nt++){
      int c  = wc*64 + nt*16 + mq;
      int fc = ks*4 + quad;
      bf[nt] = *(const f16x8*)(wh + (fc*128 + c)*8);
    }
    #pragma unroll
    for(int mt=0; mt<4; mt++)
      #pragma unroll
      for(int nt=0; nt<4; nt++)
        acc[mt][nt] = __builtin_amdgcn_mfma_f32_16x16x32_f16(af[mt], bf[nt], acc[mt][nt], 0,0,0);
  }
  __syncthreads();          // xs dead -> reuse as tanh tile
  f16* tt = xs;             // [128][136]
  f16* hpb = hpB + (long)(b*8+h)*128*128*8;
  #pragma unroll
  for(int mt=0; mt<4; mt++){
    #pragma unroll
    for(int nt=0; nt<4; nt++){
      int c = wc*64 + nt*16 + mq;
      f16x4 pk;
      #pragma unroll
      for(int rg=0; rg<4; rg++){
        float v = acc[mt][nt][rg];
        pk[rg] = (f16)v;
        int il = wr*64 + mt*16 + quad*4 + rg;    // 0..127
        float e2 = __expf(2.0f*v);
        float th = 1.0f - 2.0f*__builtin_amdgcn_rcpf(e2 + 1.0f);
        tt[il*136 + c] = (f16)th;
      }
      int il0 = wr*64 + mt*16 + quad*4;
      int inode = i0 + il0;
      *(f16x4*)(hpb + ((long)(inode>>3)*128 + c)*8 + (inode&7)) = pk;  // 8B packed store
    }
  }
  __syncthreads();
  {
    int r = t>>1, hf = t&1;
    float s_p = 0.f, d_p = 0.f;
    #pragma unroll
    for(int q=0;q<8;q++){
      f16x8 tv = *(const f16x8*)(tt + r*136 + hf*64 + q*8);
      #pragma unroll
      for(int j=0;j<8;j++){
        float tvf = (float)tv[j];
        int c = hf*64 + q*8 + j;
        s_p = fmaf(tvf, asl[c], s_p);
        d_p = fmaf(tvf, adl[c], d_p);
      }
    }
    s_p += __shfl_xor(s_p, 1);
    d_p += __shfl_xor(d_p, 1);
    if (hf == 0){
      sarr[(b*8+h)*1024 + i0 + r] = s_p;
      darr[(b*8+h)*1024 + i0 + r] = d_p;
    }
  }
}

// ---------------- attention (R5 structure at 5 blocks/CU, depth-1 prefetch) ----------------
// grid: 1024 blocks: bid = it*64 + bh  (same-bh blocks -> XCD bh%8 == h, matching k_hp)
// R10: attn is latency-bound (R2/R8: added VALU work transfers ~1:1; no pipe >35%
// of dispatch time).  Systematic fix = more TLP: occupancy 4 -> 5 blocks/CU
// (LDS 23KB x5 = 115KB ok; VGPR must fit 102 at 5 waves/SIMD).  bf depth-2 (48 VGPR)
// dropped to static double-buffer bf[2][4] depth-1 (32 VGPR, ~90 total, no spill).
// P stays in LDS, built cooperatively (R8 register-P was 4x duplicated VALU work);
// plain __syncthreads (R6 non-draining neutral); 64-col phases (R7 128-col regressed).
__global__ __launch_bounds__(256,5) void k_attn(
    const f16* __restrict__ hpB,      // [B*H][128][128][8]  (jc, c, e)
    const float* __restrict__ sarr, const float* __restrict__ darr,
    const unsigned* __restrict__ am,  // [B*1024][32]
    f16* __restrict__ part)           // [64][1024][128] f16, normalized * 0.125
{
  __shared__ float ddl[1024];         // log2e-scaled d, all columns
  __shared__ float wred[4];
  __shared__ float zl[64];
  __shared__ f16 Pl[2][64*72];        // P tiles, row stride 72 f16 (144B, 16B aligned)
  int t = threadIdx.x;
  int bid = blockIdx.x;
  int bh = bid & 63, it = bid >> 6;
  int i0 = it*64;
  int b = bh >> 3;

  int lane = t&63, wv = t>>6;
  int mq = lane&15, quad = lane>>4;
  const f16* hpb = hpB + (long)bh*128*128*8;

  // stage scaled d (all 1024) + global max of d
  {
    float4 v = *(const float4*)(darr + bh*1024 + t*4);
    float mx = fmaxf(fmaxf(v.x,v.y), fmaxf(v.z,v.w));
    #pragma unroll
    for(int o=1;o<64;o<<=1) mx = fmaxf(mx, __shfl_xor(mx, o));
    if (lane == 0) wred[wv] = mx;
    *(float4*)(ddl + t*4) = make_float4(v.x*L2E, v.y*L2E, v.z*L2E, v.w*L2E);
  }

  int prow = t>>2, pg = t&3;          // row 0..63, 16-col group 0..3
  float srowl = sarr[bh*1024 + i0 + prow] * L2E;
  const unsigned* amrow = am + ((long)(b*1024 + i0 + prow))*32;
  int wsel = pg >> 1, wsh = (pg&1)*16;

  // prefetch B fragments for tile 0 + mask words for tiles 0/1 (no LDS dep yet)
  f16x8 bf[2][4];
  #pragma unroll
  for(int kk=0;kk<2;kk++)
    #pragma unroll
    for(int nt=0;nt<2;nt++){
      int c  = wv*32 + nt*16 + mq;
      bf[0][kk*2+nt] = *(const f16x8*)(hpb + ((long)(kk*4 + quad)*128 + c)*8);
    }
  unsigned wcur = amrow[wsel];
  unsigned wnx  = amrow[2 + wsel];

  __syncthreads();
  float Dml = fmaxf(fmaxf(wred[0],wred[1]), fmaxf(wred[2],wred[3])) * L2E;
  float ml = srowl + Dml;
  float mrowl = fmaxf(ml, 0.2f*ml);   // log2-domain upper bound of masked scores

  f32x4 acc[4][2];
  #pragma unroll
  for(int a=0;a<4;a++){ acc[a][0] = (f32x4){0.f,0.f,0.f,0.f}; acc[a][1] = (f32x4){0.f,0.f,0.f,0.f}; }
  float zacc = 0.f;
  f16x8 zerov = (f16x8){0,0,0,0,0,0,0,0};

  // batched sparse P-fill (R4): ctz-chain extracts up to 4 indices, the 4 LDS loads
  // issue together (one ~120cy latency), rare >4-bit fallback loop
#define PFILL(BUF, WORDSRC, DBASE)                                        \
  {                                                                       \
    f16* myp = Pl[BUF] + prow*72 + pg*16;                                 \
    *(f16x8*)myp = zerov; *(f16x8*)(myp+8) = zerov;                       \
    unsigned word = ((WORDSRC) >> wsh) & 0xffffu;                         \
    const float* dloc = ddl + (DBASE) + pg*16;                            \
    if (word){                                                            \
      int n = __popc(word);                                               \
      unsigned w = word;                                                  \
      int j0 = __builtin_ctz(w); w &= w-1u;                               \
      int j1 = w ? __builtin_ctz(w) : j0; w = w ? (w & (w-1u)) : 0u;      \
      int j2 = w ? __builtin_ctz(w) : j0; w = w ? (w & (w-1u)) : 0u;      \
      int j3 = w ? __builtin_ctz(w) : j0;                                 \
      unsigned wrest = w ? (w & (w-1u)) : 0u;                             \
      float v0 = dloc[j0], v1 = dloc[j1], v2 = dloc[j2], v3 = dloc[j3];   \
      float x0 = srowl+v0, x1 = srowl+v1, x2 = srowl+v2, x3 = srowl+v3;   \
      float e0 = __builtin_amdgcn_exp2f(fmaxf(x0,0.2f*x0) - mrowl);       \
      float e1 = __builtin_amdgcn_exp2f(fmaxf(x1,0.2f*x1) - mrowl);      \
      float e2 = __builtin_amdgcn_exp2f(fmaxf(x2,0.2f*x2) - mrowl);      \
      float e3 = __builtin_amdgcn_exp2f(fmaxf(x3,0.2f*x3) - mrowl);      \
      zacc += e0; myp[j0] = (f16)e0;                                      \
      if (n > 1){ zacc += e1; myp[j1] = (f16)e1; }                        \
      if (n > 2){ zacc += e2; myp[j2] = (f16)e2; }                        \
      if (n > 3){ zacc += e3; myp[j3] = (f16)e3; }                        \
      while (wrest){                                                      \
        int j = __builtin_ctz(wrest); wrest &= wrest-1u;                  \
        float xl = srowl + dloc[j];                                       \
        float e  = __builtin_amdgcn_exp2f(fmaxf(xl,0.2f*xl) - mrowl);     \
        zacc += e; myp[j] = (f16)e;                                       \
      }                                                                   \
    }                                                                     \
  }

  PFILL(0, wcur, 0)
  __syncthreads();

  #pragma unroll
  for(int jt=0; jt<16; jt++){
    if (jt < 15){
      // prefetch B fragments for tile jt+1 into the other register buffer
      #pragma unroll
      for(int kk=0;kk<2;kk++)
        #pragma unroll
        for(int nt=0;nt<2;nt++){
          int c  = wv*32 + nt*16 + mq;
          int jc = (jt+1)*8 + kk*4 + quad;
          bf[(jt+1)&1][kk*2+nt] = *(const f16x8*)(hpb + ((long)jc*128 + c)*8);
        }
      unsigned wfut = (jt < 14) ? amrow[(jt+2)*2 + wsel] : 0u;
      // fill tile jt+1 into the other LDS buffer (disjoint from MFMA reads of tile jt)
      PFILL((jt+1)&1, wnx, (jt+1)*64)
      wnx = wfut;
    }
    const f16* Pc = Pl[jt&1];
    #pragma unroll
    for(int kk=0;kk<2;kk++){
      #pragma unroll
      for(int mt=0;mt<4;mt++){
        f16x8 a = *(const f16x8*)(Pc + (mt*16+mq)*72 + kk*32 + quad*8);
        #pragma unroll
        for(int nt=0;nt<2;nt++)
          acc[mt][nt] = __builtin_amdgcn_mfma_f32_16x16x32_f16(a, bf[jt&1][kk*2+nt], acc[mt][nt], 0,0,0);
      }
    }
    __syncthreads();
  }
#undef PFILL

  // full softmax denominator per row (4-lane group covers all 1024 cols)
  zacc += __shfl_xor(zacc, 1);
  zacc += __shfl_xor(zacc, 2);
  if (pg == 0) zl[prow] = zacc;
  __syncthreads();

  // normalize + head-prescale, transpose through LDS for coalesced f16x8 stores
  f16* Ps = (f16*)Pl;                  // [64][136] f16 (272B stride, 16B aligned)
  #pragma unroll
  for(int mt=0;mt<4;mt++){
    #pragma unroll
    for(int rg=0;rg<4;rg++){
      int il = mt*16 + quad*4 + rg;
      float zi = 0.125f * __builtin_amdgcn_rcpf(zl[il]);
      #pragma unroll
      for(int nt=0;nt<2;nt++){
        int c = wv*32 + nt*16 + mq;
        Ps[il*136 + c] = (f16)(acc[mt][nt][rg] * zi);
      }
    }
  }
  __syncthreads();
  {
    int r = t>>2, g = t&3;
    f16* dst = part + ((long)bh*1024 + i0 + r)*128 + g*32;
    const f16* srcp = Ps + r*136 + g*32;
    *(f16x8*)(dst)    = *(const f16x8*)(srcp);
    *(f16x8*)(dst+8)  = *(const f16x8*)(srcp+8);
    *(f16x8*)(dst+16) = *(const f16x8*)(srcp+16);
    *(f16x8*)(dst+24) = *(const f16x8*)(srcp+24);
  }
}

// ---------------- finalize: sum heads (already normalized+prescaled), bias(+relu), partial node-max ----------------
// 512 blocks x 256: block covers one b, 16 nodes, all 128 channels
__global__ void k_fin(const f16* __restrict__ part, const float* __restrict__ bias,
                      f16* __restrict__ x16, float* __restrict__ pmax, int do_relu){
  __shared__ float pm[16][128];
  int t = threadIdx.x;
  int idx = blockIdx.x*256 + t;   // b(3)|n(10)|c8(4)
  int c8 = idx & 15, n = (idx>>4)&1023, b = idx>>14;
  float s[8];
  #pragma unroll
  for(int j=0;j<8;j++) s[j] = 0.f;
  #pragma unroll
  for(int h=0;h<8;h++){
    int bh = b*8 + h;
    f16x8 p0 = *(const f16x8*)(part + ((long)bh*1024 + n)*128 + c8*8);
    #pragma unroll
    for(int j=0;j<8;j++) s[j] += (float)p0[j];
  }
  f16x8 h8;
  float ov[8];
  #pragma unroll
  for(int j=0;j<8;j++){
    float v = s[j] + bias[c8*8 + j];
    if (do_relu) v = fmaxf(v, 0.f);
    ov[j] = v;
    h8[j] = (f16)v;
  }
  if (x16) *(f16x8*)(x16 + ((long)(b*1024+n))*128 + c8*8) = h8;
  #pragma unroll
  for(int j=0;j<8;j++) pm[n&15][c8*8+j] = ov[j];
  __syncthreads();
  if (t < 128){
    float m = pm[0][t];
    #pragma unroll
    for(int r=1;r<16;r++) m = fmaxf(m, pm[r][t]);
    pmax[blockIdx.x*128 + t] = m;   // [b*64+chunk][128]
  }
}

// ---------------- final: max over chunks + predictor ----------------
// 8 blocks x 256.  Coalesced chunk-max: lanes read consecutive channels (256B/wave);
// two half-partials combined in LDS.
__global__ void k_pool2(const float* __restrict__ pmax, const float* __restrict__ pw,
                        const float* __restrict__ pb, float* __restrict__ out){
  __shared__ float ph[2][384];
  __shared__ float pl[384];
  int b = blockIdx.x, t = threadIdx.x;
  int c = t & 127, half = t >> 7;
  #pragma unroll
  for(int l=0;l<3;l++){
    const float* p = pmax + l*65536 + b*8192 + half*32*128 + c;
    float m = -3.4e38f;
    #pragma unroll 8
    for(int kk=0;kk<32;kk++) m = fmaxf(m, p[kk*128]);
    ph[half][l*128 + c] = m;
  }
  __syncthreads();
  for(int f = t; f < 384; f += 256) pl[f] = fmaxf(ph[0][f], ph[1][f]);
  __syncthreads();
  if (t < 64){
    float a0 = 0.f, a1 = 0.f;
    #pragma unroll
    for(int k=0;k<6;k++){
      int f = t + 64*k;
      float v = pl[f];
      a0 = fmaf(v, pw[f*2],   a0);
      a1 = fmaf(v, pw[f*2+1], a1);
    }
    #pragma unroll
    for(int o=1;o<64;o<<=1){ a0 += __shfl_xor(a0,o); a1 += __shfl_xor(a1,o); }
    if (t == 0){ out[b*2] = a0 + pb[0]; out[b*2+1] = a1 + pb[1]; }
  }
}

// ---------------- launcher ----------------
extern "C" void kernel_launch(void* const* d_in, const int* in_sizes, int n_in,
                              void* d_out, int out_size, void* d_ws, size_t ws_size,
                              hipStream_t stream) {
  const float* x   = (const float*)d_in[0];
  const float* adj = (const float*)d_in[1];
  const float* w1  = (const float*)d_in[2];
  const float* as1 = (const float*)d_in[3];
  const float* ad1 = (const float*)d_in[4];
  const float* b1  = (const float*)d_in[5];
  const float* w2  = (const float*)d_in[6];
  const float* as2 = (const float*)d_in[7];
  const float* ad2 = (const float*)d_in[8];
  const float* b2  = (const float*)d_in[9];
  const float* w3  = (const float*)d_in[10];
  const float* as3 = (const float*)d_in[11];
  const float* ad3 = (const float*)d_in[12];
  const float* b3  = (const float*)d_in[13];
  const float* pw  = (const float*)d_in[14];
  const float* pb  = (const float*)d_in[15];

  char* ws = (char*)d_ws;
  f16*      x16a = (f16*)ws;                 ws += (size_t)1048576*2;
  f16*      x16b = (f16*)ws;                 ws += (size_t)1048576*2;
  f16*      wB   = (f16*)ws;                 ws += (size_t)393216*2;
  unsigned* am   = (unsigned*)ws;            ws += (size_t)8*1024*32*4;
  f16*      hpB  = (f16*)ws;                 ws += (size_t)8*8*1024*128*2;
  float*    sarr = (float*)ws;               ws += (size_t)65536*4;
  float*    darr = (float*)ws;               ws += (size_t)65536*4;
  f16*      part = (f16*)ws;                 ws += (size_t)64*1024*128*2;
  float*    pmax = (float*)ws;               ws += (size_t)3*512*128*4;

  k_pre<<<2752, 256, 0, stream>>>(x, x16a, w1, w2, w3, wB, adj, am);

  // layer 1
  k_hp  <<<512, 256, 0, stream>>>(x16a, wB,            as1, ad1, hpB, sarr, darr);
  k_attn<<<1024,256, 0, stream>>>(hpB, sarr, darr, am, part);
  k_fin <<<512, 256, 0, stream>>>(part, b1, x16b, pmax,           1);
  // layer 2
  k_hp  <<<512, 256, 0, stream>>>(x16b, wB + 131072,   as2, ad2, hpB, sarr, darr);
  k_attn<<<1024,256, 0, stream>>>(hpB, sarr, darr, am, part);
  k_fin <<<512, 256, 0, stream>>>(part, b2, x16a, pmax + 65536,   1);
  // layer 3
  k_hp  <<<512, 256, 0, stream>>>(x16a, wB + 262144,   as3, ad3, hpB, sarr, darr);
  k_attn<<<1024,256, 0, stream>>>(hpB, sarr, darr, am, part);
  k_fin <<<512, 256, 0, stream>>>(part, b3, nullptr, pmax + 131072, 0);

  k_pool2<<<8, 256, 0, stream>>>(pmax, pw, pb, (float*)d_out);
}